// Round 5
// baseline (680.911 us; speedup 1.0000x reference)
//
#include <hip/hip_runtime.h>
#include <hip/hip_bf16.h>

typedef __attribute__((ext_vector_type(8))) short v8s;            // 8 x bf16 (4 VGPRs) MFMA A/B
typedef __attribute__((ext_vector_type(8))) unsigned short u16x8;
typedef __attribute__((ext_vector_type(4))) float v4f;            // 16x16 MFMA C/D
typedef __attribute__((ext_vector_type(16))) float f32x16;        // 32x32 MFMA C/D

#define MFMA16(a, b, c) __builtin_amdgcn_mfma_f32_16x16x32_bf16((a), (b), (c), 0, 0, 0)
#define MFMA32(a, b, c) __builtin_amdgcn_mfma_f32_32x32x16_bf16((a), (b), (c), 0, 0, 0)

// async global->LDS, 16B per lane; LDS dest = wave-uniform base + lane*16
#define GLL16(g, l)                                                        \
  __builtin_amdgcn_global_load_lds(                                        \
      (const __attribute__((address_space(1))) unsigned int*)(g),          \
      (__attribute__((address_space(3))) unsigned int*)(l), 16, 0, 0)

#if __has_builtin(__builtin_amdgcn_exp2f)
__device__ __forceinline__ float exp2n(float x) { return __builtin_amdgcn_exp2f(x); }
#else
__device__ __forceinline__ float exp2n(float x) {
  float r; asm("v_exp_f32 %0, %1" : "=v"(r) : "v"(x)); return r;
}
#endif

__device__ __forceinline__ unsigned short f2bf(float f) {
  union { float f; unsigned u; } v; v.f = f;
  unsigned r = v.u + 0x7fffu + ((v.u >> 16) & 1u);   // RNE
  return (unsigned short)(r >> 16);
}

// RNE pack of two f32 -> bf16x2 (lo in low half) in one VOP3
__device__ __forceinline__ unsigned cvtpk(float lo, float hi) {
  unsigned r;
  asm("v_cvt_pk_bf16_f32 %0, %1, %2" : "=v"(r) : "v"(lo), "v"(hi));
  return r;
}
// gfx950: swap high 32 lanes of a with low 32 lanes of b (both modified)
__device__ __forceinline__ void pl32swap(unsigned& a, unsigned& b) {
  asm("v_permlane32_swap_b32 %0, %1" : "+v"(a), "+v"(b));
}

// ---- 64KB LDS union shared by all phases (cap is 64KB static) ----
union __align__(16) SMem {
  float slab[16384];                                           // GN phase
  struct { unsigned short As[128][64]; unsigned short Bs[128][64]; } g;   // GEMM
  struct { unsigned short Ks[2][128][64]; unsigned short Vs[2][2][64][64]; } a; // attn
};

// Grid-wide barrier. SAFE by construction: grid=512 blocks, 64KB LDS + <=256 VGPR
// (launch_bounds(256,2)) -> exactly 2 blocks/CU x 256 CUs co-resident, no deadlock.
// threadfence = agent-scope fence (buffer_wbl2/inv) -> handles cross-XCD L2
// non-coherence for the ordinary stores each phase makes (G16).
__device__ __forceinline__ void gridbar(unsigned* c, unsigned nblk) {
  __threadfence();                 // per-thread release of this phase's stores
  __syncthreads();
  if (threadIdx.x == 0) {
    __hip_atomic_fetch_add(c, 1u, __ATOMIC_RELEASE, __HIP_MEMORY_SCOPE_AGENT);
    while (__hip_atomic_load(c, __ATOMIC_ACQUIRE, __HIP_MEMORY_SCOPE_AGENT) < nblk)
      __builtin_amdgcn_s_sleep(8);
  }
  __syncthreads();
  __threadfence();                 // acquire: drop stale lines before next phase reads
}

// block-uniform ticket draw, broadcast through LDS slot 0 (re-staged by every phase)
__device__ __forceinline__ int next_job(SMem& sh, unsigned* tick) {
  __syncthreads();                 // prior job fully done with LDS
  if (threadIdx.x == 0)
    *(volatile unsigned*)&sh.slab[0] = atomicAdd(tick, 1u);
  __syncthreads();
  const int j = (int)*(volatile unsigned*)&sh.slab[0];
  __syncthreads();                 // everyone read before job body reuses LDS
  return j;
}

// ---- phase 1a: GroupNorm stats+normalize+transpose for one (b,group) slab ----
__device__ void gn_job(SMem& sh, int bg, const float* __restrict__ x,
                       const float* __restrict__ gsc, const float* __restrict__ gbi,
                       unsigned short* __restrict__ xnT) {
  float* xsf = sh.slab;
  const int b = bg >> 5, g = bg & 31;
  const int tid = threadIdx.x;
  const float4* xp4 = (const float4*)(x + (size_t)bg * 16384);
  float4* xs4 = (float4*)xsf;
  float s = 0.f, ss = 0.f;
  #pragma unroll
  for (int k = 0; k < 16; ++k) {
    const int i = k * 256 + tid;
    float4 v = xp4[i];
    xs4[i] = v;
    s  += (v.x + v.y) + (v.z + v.w);
    ss += (v.x * v.x + v.y * v.y) + (v.z * v.z + v.w * v.w);
  }
  #pragma unroll
  for (int d = 1; d < 64; d <<= 1) { s += __shfl_xor(s, d); ss += __shfl_xor(ss, d); }
  // cross-wave reduce through slab slots 0..9 (save/clobber/restore)
  __syncthreads();
  float save = 0.f;
  if (tid < 10) save = xsf[tid];
  __syncthreads();
  if ((tid & 63) == 0) { xsf[(tid >> 6) * 2] = s; xsf[(tid >> 6) * 2 + 1] = ss; }
  __syncthreads();
  if (tid == 0) {
    const float S  = xsf[0] + xsf[2] + xsf[4] + xsf[6];
    const float SS = xsf[1] + xsf[3] + xsf[5] + xsf[7];
    const float mu  = S * (1.f / 16384.f);
    const float var = SS * (1.f / 16384.f) - mu * mu;
    xsf[8] = mu; xsf[9] = rsqrtf(var + 1e-5f);
  }
  __syncthreads();
  const float mu = xsf[8], rs = xsf[9];
  __syncthreads();
  if (tid < 10) xsf[tid] = save;
  __syncthreads();
  float scv[16], biv[16];
  #pragma unroll
  for (int j = 0; j < 16; ++j) {
    scv[j] = gsc[g * 16 + j] * rs;
    biv[j] = gbi[g * 16 + j] - mu * scv[j];
  }
  unsigned short* dp = xnT + (size_t)b * 1024 * 512 + g * 16;
  #pragma unroll
  for (int k = 0; k < 4; ++k) {
    const int l = k * 256 + tid;
    u16x8 o0, o1;
    #pragma unroll
    for (int j = 0; j < 8; ++j) o0[j] = f2bf(xsf[j * 1024 + l] * scv[j] + biv[j]);
    #pragma unroll
    for (int j = 0; j < 8; ++j) o1[j] = f2bf(xsf[(8 + j) * 1024 + l] * scv[8 + j] + biv[8 + j]);
    *(u16x8*)(dp + (size_t)l * 512)     = o0;
    *(u16x8*)(dp + (size_t)l * 512 + 8) = o1;
  }
}

// ---- phases 2/4: 128xNT MFMA GEMM job, BK=64, xor-swizzled 128B LDS rows ----
template <bool QKV, int NT>
__device__ void gemm_job(SMem& sh, int job,
                         const unsigned short* __restrict__ A,
                         const unsigned short* __restrict__ BT,
                         const float* __restrict__ bias,
                         const float* __restrict__ xres,
                         float* __restrict__ outf,
                         unsigned short* __restrict__ qT,
                         unsigned short* __restrict__ kT,
                         unsigned short* __restrict__ vO) {
  constexpr int K = 512;
  constexpr int NFR = NT / 32;
  constexpr int NJOB = 16 + NT / 8;
  constexpr int GX = QKV ? 8 : 16;
  constexpr int GY = QKV ? 12 : 4;
  const int n0 = (job % GX) * NT;
  const int m0 = ((job / GX) % GY) * 128;
  const int b  = job / (GX * GY);
  const unsigned short* Bp = BT + (size_t)b * 1024 * K;

  auto& As = sh.g.As;
  auto& Bs = sh.g.Bs;

  const int tid = threadIdx.x, lane = tid & 63, w = tid >> 6;
  const int quad = lane >> 4, l15 = lane & 15;
  const int wm = (w >> 1) * 64, wn = (w & 1) * (NT / 2);
  const int srow = lane >> 3;
  const int scol = ((lane & 7) ^ srow) * 8;
  const int ck0 = ((quad ^ (l15 & 7)) * 8);
  const int ck1 = ck0 ^ 32;
  const unsigned short* Asf = &As[0][0];
  const unsigned short* Bsf = &Bs[0][0];

  v4f acc[4][NFR];
  #pragma unroll
  for (int i = 0; i < 4; ++i)
    #pragma unroll
    for (int j = 0; j < NFR; ++j) acc[i][j] = (v4f){0.f, 0.f, 0.f, 0.f};

  for (int kk = 0; kk < K; kk += 64) {
    __syncthreads();
    #pragma unroll
    for (int jj = 0; jj < NJOB / 4; ++jj) {
      const int job2 = w * (NJOB / 4) + jj;
      if (job2 < 16) {
        GLL16(A + (size_t)(m0 + job2 * 8 + srow) * K + kk + scol, &As[job2 * 8][0]);
      } else {
        const int j2 = job2 - 16;
        GLL16(Bp + (size_t)(n0 + j2 * 8 + srow) * K + kk + scol, &Bs[j2 * 8][0]);
      }
    }
    __syncthreads();
    #pragma unroll
    for (int h = 0; h < 2; ++h) {
      const int ck = h ? ck1 : ck0;
      v8s af[4], bf[NFR];
      #pragma unroll
      for (int mt = 0; mt < 4; ++mt) af[mt] = *(const v8s*)(Asf + (wm + mt * 16 + l15) * 64 + ck);
      #pragma unroll
      for (int nt = 0; nt < NFR; ++nt) bf[nt] = *(const v8s*)(Bsf + (wn + nt * 16 + l15) * 64 + ck);
      #pragma unroll
      for (int mt = 0; mt < 4; ++mt)
        #pragma unroll
        for (int nt = 0; nt < NFR; ++nt)
          acc[mt][nt] = MFMA16(af[mt], bf[nt], acc[mt][nt]);
    }
  }

  if (QKV) {
    const int bh8 = b * 8;
    const float cs = 0.18033688011112042f;   // 0.125 * log2(e), folded into q
    #pragma unroll
    for (int mt = 0; mt < 4; ++mt) {
      const int m4 = m0 + wm + mt * 16 + quad * 4;
      const int h = m4 / 192;
      const int rr = m4 - h * 192;
      const int part = rr >> 6;                          // 0=q 1=k 2=v
      const int ch = rr & 63;
      const float b0 = bias[m4], b1 = bias[m4 + 1], b2 = bias[m4 + 2], b3 = bias[m4 + 3];
      #pragma unroll
      for (int nt = 0; nt < NFR; ++nt) {
        const int n = n0 + wn + nt * 16 + l15;
        v4f a = acc[mt][nt];
        const float v0 = a[0] + b0, v1 = a[1] + b1, v2 = a[2] + b2, v3 = a[3] + b3;
        if (part == 0) {
          ushort4 st4;
          st4.x = f2bf(v0 * cs); st4.y = f2bf(v1 * cs);
          st4.z = f2bf(v2 * cs); st4.w = f2bf(v3 * cs);
          *(ushort4*)(qT + ((size_t)(bh8 + h) * 1024 + n) * 64 + ch) = st4;
        } else if (part == 1) {
          ushort4 st4;
          st4.x = f2bf(v0); st4.y = f2bf(v1); st4.z = f2bf(v2); st4.w = f2bf(v3);
          *(ushort4*)(kT + ((size_t)(bh8 + h) * 1024 + n) * 64 + ch) = st4;
        } else {
          unsigned short* dp = vO + ((size_t)(bh8 + h) * 64 + ch) * 1024 + n;
          dp[0] = f2bf(v0); dp[1024] = f2bf(v1); dp[2048] = f2bf(v2); dp[3072] = f2bf(v3);
        }
      }
    }
  } else {
    #pragma unroll
    for (int mt = 0; mt < 4; ++mt) {
      const int m4 = m0 + wm + mt * 16 + quad * 4;
      const float b0 = bias[m4], b1 = bias[m4 + 1], b2 = bias[m4 + 2], b3 = bias[m4 + 3];
      #pragma unroll
      for (int nt = 0; nt < NFR; ++nt) {
        const int n = n0 + wn + nt * 16 + l15;
        const size_t i0 = ((size_t)b * 512 + m4) * 1024 + n;
        outf[i0]        = xres[i0]        + acc[mt][nt][0] + b0;
        outf[i0 + 1024] = xres[i0 + 1024] + acc[mt][nt][1] + b1;
        outf[i0 + 2048] = xres[i0 + 2048] + acc[mt][nt][2] + b2;
        outf[i0 + 3072] = xres[i0 + 3072] + acc[mt][nt][3] + b3;
      }
    }
  }
}

// ---- phase 3: flash attention job, 128q/block, 32 q/wave (R4 geometry) ----
__device__ void attn_job(SMem& sh, int bid,
                         const unsigned short* __restrict__ qT,
                         const unsigned short* __restrict__ kT,
                         const unsigned short* __restrict__ vv,
                         unsigned short* __restrict__ aT) {
  const int bh = bid & 63;                  // XCD = bid%8 = bh%8 (same as split grid)
  const int t0 = (bid >> 6) * 128;
  const unsigned short* qb = qT + (size_t)bh * 1024 * 64;
  const unsigned short* kb = kT + (size_t)bh * 1024 * 64;
  const unsigned short* vb = vv + (size_t)bh * 64 * 1024;

  auto& Ks = sh.a.Ks;
  auto& Vs = sh.a.Vs;

  const int tid = threadIdx.x, w = tid >> 6, lane = tid & 63;
  const int l31 = lane & 31, h = lane >> 5;
  const int srow = lane >> 3;
  const int scol = ((lane & 7) ^ srow) * 8;

  // ---- stage Q (128 rows) through Ks[0], read B-frags ----
  #pragma unroll
  for (int jj = 0; jj < 4; ++jj) {
    const int seg = w * 4 + jj;
    GLL16(qb + (size_t)(t0 + seg * 8 + srow) * 64 + scol, &Ks[0][0][0] + seg * 8 * 64);
  }
  __syncthreads();
  v8s qf[4];
  {
    const int row = w * 32 + l31;
    const unsigned short* qr = &Ks[0][0][0] + row * 64;
    const int rx = row & 7;
    #pragma unroll
    for (int kb2 = 0; kb2 < 4; ++kb2)
      qf[kb2] = *(const v8s*)(qr + ((kb2 * 2 + h) ^ rx) * 8);
  }
  __syncthreads();

  // ---- stage K/V tile 0 ----
  #pragma unroll
  for (int jj = 0; jj < 8; ++jj) {
    const int j = w * 8 + jj;
    if (j < 16) {
      GLL16(kb + (size_t)(j * 8 + srow) * 64 + scol, &Ks[0][j * 8][0]);
    } else {
      const int j2 = j - 16, hf = j2 >> 3, cg = (j2 & 7) * 8;
      GLL16(vb + (size_t)(cg + srow) * 1024 + hf * 64 + scol, &Vs[0][hf][cg][0]);
    }
  }

  f32x16 o[2];
  #pragma unroll
  for (int cb = 0; cb < 2; ++cb)
    #pragma unroll
    for (int r = 0; r < 16; ++r) o[cb][r] = 0.f;
  float lsum = 0.f;

  for (int it = 0; it < 8; ++it) {
    __syncthreads();
    if (it + 1 < 8) {
      const int s1 = (it + 1) * 128, bp1 = (it + 1) & 1;
      #pragma unroll
      for (int jj = 0; jj < 8; ++jj) {
        const int j = w * 8 + jj;
        if (j < 16) {
          GLL16(kb + (size_t)(s1 + j * 8 + srow) * 64 + scol, &Ks[bp1][j * 8][0]);
        } else {
          const int j2 = j - 16, hf = j2 >> 3, cg = (j2 & 7) * 8;
          GLL16(vb + (size_t)(cg + srow) * 1024 + s1 + hf * 64 + scol,
                &Vs[bp1][hf][cg][0]);
        }
      }
    }
    const int buf = it & 1;

    #pragma unroll
    for (int hf = 0; hf < 2; ++hf) {
      const unsigned short* Kb = &Ks[buf][hf * 64][0];
      const unsigned short* Vb = &Vs[buf][hf][0][0];

      v8s kf[2][4], vf[2][4];
      #pragma unroll
      for (int sb = 0; sb < 2; ++sb) {
        const int row = sb * 32 + l31, rx = row & 7;
        const unsigned short* kr = Kb + row * 64;
        #pragma unroll
        for (int kb2 = 0; kb2 < 4; ++kb2)
          kf[sb][kb2] = *(const v8s*)(kr + ((kb2 * 2 + h) ^ rx) * 8);
      }
      #pragma unroll
      for (int cb = 0; cb < 2; ++cb) {
        const int row = cb * 32 + l31, rx = row & 7;
        const unsigned short* vr = Vb + row * 64;
        #pragma unroll
        for (int i = 0; i < 4; ++i)
          vf[cb][i] = *(const v8s*)(vr + ((i * 2 + h) ^ rx) * 8);
      }

      #pragma unroll
      for (int sb = 0; sb < 2; ++sb) {
        f32x16 sa = {0.f,0.f,0.f,0.f,0.f,0.f,0.f,0.f,0.f,0.f,0.f,0.f,0.f,0.f,0.f,0.f};
        #pragma unroll
        for (int kb2 = 0; kb2 < 4; ++kb2)
          sa = MFMA32(kf[sb][kb2], qf[kb2], sa);
        float p[16]; float rsum = 0.f;
        #pragma unroll
        for (int r = 0; r < 16; ++r) { p[r] = exp2n(sa[r]); rsum += p[r]; }
        lsum += rsum;
        unsigned c0 = cvtpk(p[0], p[1]),  c1 = cvtpk(p[2], p[3]);
        unsigned c2 = cvtpk(p[4], p[5]),  c3 = cvtpk(p[6], p[7]);
        pl32swap(c0, c2); pl32swap(c1, c3);
        unsigned c4 = cvtpk(p[8], p[9]),  c5 = cvtpk(p[10], p[11]);
        unsigned c6 = cvtpk(p[12], p[13]), c7 = cvtpk(p[14], p[15]);
        pl32swap(c4, c6); pl32swap(c5, c7);
        union { v8s v; unsigned u[4]; } pa0, pa1;
        pa0.u[0] = c0; pa0.u[1] = c1; pa0.u[2] = c2; pa0.u[3] = c3;
        pa1.u[0] = c4; pa1.u[1] = c5; pa1.u[2] = c6; pa1.u[3] = c7;
        #pragma unroll
        for (int cb = 0; cb < 2; ++cb) {
          o[cb] = MFMA32(pa0.v, vf[cb][sb * 2 + 0], o[cb]);
          o[cb] = MFMA32(pa1.v, vf[cb][sb * 2 + 1], o[cb]);
        }
      }
    }
  }

  const int b = bh >> 3, hd = bh & 7;
  lsum += __shfl_xor(lsum, 32);
  #pragma unroll
  for (int r = 0; r < 16; ++r) {
    const int trow = (r & 3) + 8 * (r >> 2) + 4 * h;
    const float inv = 1.0f / __shfl(lsum, trow);
    const int t = t0 + w * 32 + trow;
    unsigned short* dst = aT + ((size_t)b * 1024 + t) * 512 + hd * 64;
    dst[l31]      = f2bf(o[0][r] * inv);
    dst[32 + l31] = f2bf(o[1][r] * inv);
  }
}

// ---- persistent mega-kernel: GN/cvt -> QKV gemm -> attn -> proj, 3 grid barriers ----
__global__ __launch_bounds__(256, 2) void fused_all(
    const float* __restrict__ qkvw, unsigned short* __restrict__ qw,
    const float* __restrict__ pjw,  unsigned short* __restrict__ pw,
    const float* __restrict__ x, const float* __restrict__ gsc,
    const float* __restrict__ gbi, unsigned short* __restrict__ xnT,
    const float* __restrict__ qkvb,
    unsigned short* __restrict__ qT, unsigned short* __restrict__ kT,
    unsigned short* __restrict__ vv, unsigned short* __restrict__ aT,
    const float* __restrict__ pjb, float* __restrict__ out,
    unsigned* ctrs) {
  __shared__ SMem sh;
  const int bid = blockIdx.x;

  // phase 1: jobs 0..255 = GN slabs; 256..511 = weight convert (1024 f4/job)
  for (;;) {
    const int j = next_job(sh, &ctrs[3]);
    if (j >= 512) break;
    if (j < 256) {
      gn_job(sh, j, x, gsc, gbi, xnT);
    } else {
      #pragma unroll
      for (int k = 0; k < 4; ++k) {
        int i = (j - 256) * 1024 + k * 256 + threadIdx.x;   // < 262144 float4s
        const float* in; unsigned short* outp;
        if (i < 196608) { in = qkvw; outp = qw; }
        else            { i -= 196608; in = pjw; outp = pw; }
        float4 v = ((const float4*)in)[i];
        ushort4 o;
        o.x = f2bf(v.x); o.y = f2bf(v.y); o.z = f2bf(v.z); o.w = f2bf(v.w);
        ((ushort4*)outp)[i] = o;
      }
    }
  }
  gridbar(&ctrs[0], 512);

  // phase 2: QKV gemm, 768 jobs, ticket-balanced
  for (;;) {
    const int j = next_job(sh, &ctrs[4]);
    if (j >= 768) break;
    gemm_job<true, 128>(sh, j, qw, xnT, qkvb, nullptr, nullptr, qT, kT, vv);
  }
  gridbar(&ctrs[1], 512);

  // phase 3: attention, 1 job/block (2 blocks/CU co-resident, as in the split kernel)
  attn_job(sh, bid, qT, kT, vv, aT);
  gridbar(&ctrs[2], 512);

  // phase 4: proj gemm + residual, 1 job/block
  gemm_job<false, 64>(sh, bid, pw, aT, pjb, x, out, nullptr, nullptr, nullptr);
}

extern "C" void kernel_launch(void* const* d_in, const int* in_sizes, int n_in,
                              void* d_out, int out_size, void* d_ws, size_t ws_size,
                              hipStream_t stream) {
  const float* x    = (const float*)d_in[0];
  const float* gsc  = (const float*)d_in[1];
  const float* gbi  = (const float*)d_in[2];
  const float* qkvw = (const float*)d_in[3];
  const float* qkvb = (const float*)d_in[4];
  const float* pjw  = (const float*)d_in[5];
  const float* pjb  = (const float*)d_in[6];
  float* out = (float*)d_out;

  unsigned short* ws  = (unsigned short*)d_ws;
  unsigned short* qw  = ws;                   //  786432  qkv weights bf16
  unsigned short* pw  = qw + 786432;          //  262144  proj weights bf16
  unsigned short* xnT = pw + 262144 + 1024;   // 4194304  [b][l][c]
  unsigned short* qT  = xnT + 4194304;        // 4194304  [bh][l][64]
  unsigned short* kT  = qT + 4194304;         // 4194304  [bh][l][64]
  unsigned short* vv  = kT + 4194304;         // 4194304  [bh][64][l]
  unsigned short* aT  = vv + 4194304;         // 4194304  [b][l][c]
  unsigned* ctrs = (unsigned*)(aT + 4194304); // 5 u32: bar0..2, tick1, tick2

  hipMemsetAsync(ctrs, 0, 32, stream);
  fused_all<<<dim3(512), dim3(256), 0, stream>>>(qkvw, qw, pjw, pw, x, gsc, gbi, xnT,
                                                 qkvb, qT, kT, vv, aT, pjb, out, ctrs);
}

// Round 6
// 233.418 us; speedup vs baseline: 2.9171x; 2.9171x over previous
//
#include <hip/hip_runtime.h>
#include <hip/hip_bf16.h>

typedef __attribute__((ext_vector_type(8))) short v8s;            // 8 x bf16 (4 VGPRs) MFMA A/B
typedef __attribute__((ext_vector_type(8))) unsigned short u16x8;
typedef __attribute__((ext_vector_type(4))) float v4f;            // 16x16 MFMA C/D
typedef __attribute__((ext_vector_type(16))) float f32x16;        // 32x32 MFMA C/D

#define MFMA16(a, b, c) __builtin_amdgcn_mfma_f32_16x16x32_bf16((a), (b), (c), 0, 0, 0)
#define MFMA32(a, b, c) __builtin_amdgcn_mfma_f32_32x32x16_bf16((a), (b), (c), 0, 0, 0)

// async global->LDS, 16B per lane; LDS dest = wave-uniform base + lane*16
#define GLL16(g, l)                                                        \
  __builtin_amdgcn_global_load_lds(                                        \
      (const __attribute__((address_space(1))) unsigned int*)(g),          \
      (__attribute__((address_space(3))) unsigned int*)(l), 16, 0, 0)

#if __has_builtin(__builtin_amdgcn_exp2f)
__device__ __forceinline__ float exp2n(float x) { return __builtin_amdgcn_exp2f(x); }
#else
__device__ __forceinline__ float exp2n(float x) {
  float r; asm("v_exp_f32 %0, %1" : "=v"(r) : "v"(x)); return r;
}
#endif

__device__ __forceinline__ unsigned short f2bf(float f) {
  union { float f; unsigned u; } v; v.f = f;
  unsigned r = v.u + 0x7fffu + ((v.u >> 16) & 1u);   // RNE
  return (unsigned short)(r >> 16);
}

// RNE pack of two f32 -> bf16x2 (lo in low half) in one VOP3
__device__ __forceinline__ unsigned cvtpk(float lo, float hi) {
  unsigned r;
  asm("v_cvt_pk_bf16_f32 %0, %1, %2" : "=v"(r) : "v"(lo), "v"(hi));
  return r;
}
// gfx950: swap high 32 lanes of a with low 32 lanes of b (both modified)
__device__ __forceinline__ void pl32swap(unsigned& a, unsigned& b) {
  asm("v_permlane32_swap_b32 %0, %1" : "+v"(a), "+v"(b));
}

// ---- fused: weight fp32->bf16 convert + GroupNorm (stats+normalize+transpose) ----
__global__ __launch_bounds__(256) void cvt_gn_kernel(const float* __restrict__ in0,
                                                     unsigned short* __restrict__ out0,
                                                     const float* __restrict__ in1,
                                                     unsigned short* __restrict__ out1,
                                                     int n0, int n1,
                                                     const float* __restrict__ x,
                                                     const float* __restrict__ gsc,
                                                     const float* __restrict__ gbi,
                                                     unsigned short* __restrict__ xnT) {
  __shared__ __align__(16) float xsf[16384];   // 64KB slab, exactly at the LDS cap
  if (blockIdx.x < 1024) {
    int i = blockIdx.x * 256 + threadIdx.x;
    const float* in; unsigned short* out;
    if (i < n0) { in = in0; out = out0; }
    else        { i -= n0; if (i >= n1) return; in = in1; out = out1; }
    float4 v = ((const float4*)in)[i];
    ushort4 o;
    o.x = f2bf(v.x); o.y = f2bf(v.y); o.z = f2bf(v.z); o.w = f2bf(v.w);
    ((ushort4*)out)[i] = o;
    return;
  }
  const int bg = blockIdx.x - 1024;            // 0..255 = b*32 + g
  const int b = bg >> 5, g = bg & 31;
  const int tid = threadIdx.x;
  const float4* xp4 = (const float4*)(x + (size_t)bg * 16384);
  float4* xs4 = (float4*)xsf;
  float s = 0.f, ss = 0.f;
  #pragma unroll
  for (int k = 0; k < 16; ++k) {
    const int i = k * 256 + tid;
    float4 v = xp4[i];
    xs4[i] = v;
    s  += (v.x + v.y) + (v.z + v.w);
    ss += (v.x * v.x + v.y * v.y) + (v.z * v.z + v.w * v.w);
  }
  #pragma unroll
  for (int d = 1; d < 64; d <<= 1) { s += __shfl_xor(s, d); ss += __shfl_xor(ss, d); }
  // cross-wave reduce through slab slots 0..9 (save/clobber/restore)
  __syncthreads();
  float save = 0.f;
  if (tid < 10) save = xsf[tid];
  __syncthreads();
  if ((tid & 63) == 0) { xsf[(tid >> 6) * 2] = s; xsf[(tid >> 6) * 2 + 1] = ss; }
  __syncthreads();
  if (tid == 0) {
    const float S  = xsf[0] + xsf[2] + xsf[4] + xsf[6];
    const float SS = xsf[1] + xsf[3] + xsf[5] + xsf[7];
    const float mu  = S * (1.f / 16384.f);
    const float var = SS * (1.f / 16384.f) - mu * mu;
    xsf[8] = mu; xsf[9] = rsqrtf(var + 1e-5f);
  }
  __syncthreads();
  const float mu = xsf[8], rs = xsf[9];
  __syncthreads();
  if (tid < 10) xsf[tid] = save;
  __syncthreads();
  float scv[16], biv[16];
  #pragma unroll
  for (int j = 0; j < 16; ++j) {
    scv[j] = gsc[g * 16 + j] * rs;
    biv[j] = gbi[g * 16 + j] - mu * scv[j];
  }
  unsigned short* dp = xnT + (size_t)b * 1024 * 512 + g * 16;
  #pragma unroll
  for (int k = 0; k < 4; ++k) {
    const int l = k * 256 + tid;
    u16x8 o0, o1;
    #pragma unroll
    for (int j = 0; j < 8; ++j) o0[j] = f2bf(xsf[j * 1024 + l] * scv[j] + biv[j]);
    #pragma unroll
    for (int j = 0; j < 8; ++j) o1[j] = f2bf(xsf[(8 + j) * 1024 + l] * scv[8 + j] + biv[8 + j]);
    *(u16x8*)(dp + (size_t)l * 512)     = o0;
    *(u16x8*)(dp + (size_t)l * 512 + 8) = o1;
  }
}

// ---------------- 128xNT MFMA GEMM, BK=64, xor-swizzled 128B LDS rows ----------------
template <bool QKV, int NT>
__global__ __launch_bounds__(256) void gemm_kernel(
    const unsigned short* __restrict__ A,
    const unsigned short* __restrict__ BT,
    const float* __restrict__ bias,
    const float* __restrict__ xres,
    float* __restrict__ outf,
    unsigned short* __restrict__ qT,
    unsigned short* __restrict__ kT,
    unsigned short* __restrict__ vO) {
  constexpr int K = 512;
  constexpr int NFR = NT / 32;              // n-frags per wave
  constexpr int NJOB = 16 + NT / 8;         // staging jobs (A:16, B:NT/8)
  const int n0 = blockIdx.x * NT, m0 = blockIdx.y * 128, b = blockIdx.z;
  const unsigned short* Bp = BT + (size_t)b * 1024 * K;

  __shared__ __align__(16) unsigned short As[128][64];
  __shared__ __align__(16) unsigned short Bs[NT][64];

  const int tid = threadIdx.x, lane = tid & 63, w = tid >> 6;
  const int quad = lane >> 4, l15 = lane & 15;
  const int wm = (w >> 1) * 64, wn = (w & 1) * (NT / 2);
  const int srow = lane >> 3;
  const int scol = ((lane & 7) ^ srow) * 8;
  const int ck0 = ((quad ^ (l15 & 7)) * 8);
  const int ck1 = ck0 ^ 32;
  const unsigned short* Asf = &As[0][0];
  const unsigned short* Bsf = &Bs[0][0];

  v4f acc[4][NFR];
  #pragma unroll
  for (int i = 0; i < 4; ++i)
    #pragma unroll
    for (int j = 0; j < NFR; ++j) acc[i][j] = (v4f){0.f, 0.f, 0.f, 0.f};

  for (int kk = 0; kk < K; kk += 64) {
    __syncthreads();
    #pragma unroll
    for (int jj = 0; jj < NJOB / 4; ++jj) {
      const int job = w * (NJOB / 4) + jj;
      if (job < 16) {
        GLL16(A + (size_t)(m0 + job * 8 + srow) * K + kk + scol, &As[job * 8][0]);
      } else {
        const int j2 = job - 16;
        GLL16(Bp + (size_t)(n0 + j2 * 8 + srow) * K + kk + scol, &Bs[j2 * 8][0]);
      }
    }
    __syncthreads();
    #pragma unroll
    for (int h = 0; h < 2; ++h) {
      const int ck = h ? ck1 : ck0;
      v8s af[4], bf[NFR];
      #pragma unroll
      for (int mt = 0; mt < 4; ++mt) af[mt] = *(const v8s*)(Asf + (wm + mt * 16 + l15) * 64 + ck);
      #pragma unroll
      for (int nt = 0; nt < NFR; ++nt) bf[nt] = *(const v8s*)(Bsf + (wn + nt * 16 + l15) * 64 + ck);
      #pragma unroll
      for (int mt = 0; mt < 4; ++mt)
        #pragma unroll
        for (int nt = 0; nt < NFR; ++nt)
          acc[mt][nt] = MFMA16(af[mt], bf[nt], acc[mt][nt]);
    }
  }

  if (QKV) {
    const int bh8 = b * 8;
    const float cs = 0.18033688011112042f;   // 0.125 * log2(e), folded into q
    #pragma unroll
    for (int mt = 0; mt < 4; ++mt) {
      const int m4 = m0 + wm + mt * 16 + quad * 4;
      const int h = m4 / 192;
      const int rr = m4 - h * 192;
      const int part = rr >> 6;                          // 0=q 1=k 2=v
      const int ch = rr & 63;
      const float b0 = bias[m4], b1 = bias[m4 + 1], b2 = bias[m4 + 2], b3 = bias[m4 + 3];
      #pragma unroll
      for (int nt = 0; nt < NFR; ++nt) {
        const int n = n0 + wn + nt * 16 + l15;
        v4f a = acc[mt][nt];
        const float v0 = a[0] + b0, v1 = a[1] + b1, v2 = a[2] + b2, v3 = a[3] + b3;
        if (part == 0) {
          ushort4 st4;
          st4.x = f2bf(v0 * cs); st4.y = f2bf(v1 * cs);
          st4.z = f2bf(v2 * cs); st4.w = f2bf(v3 * cs);
          *(ushort4*)(qT + ((size_t)(bh8 + h) * 1024 + n) * 64 + ch) = st4;
        } else if (part == 1) {
          ushort4 st4;
          st4.x = f2bf(v0); st4.y = f2bf(v1); st4.z = f2bf(v2); st4.w = f2bf(v3);
          *(ushort4*)(kT + ((size_t)(bh8 + h) * 1024 + n) * 64 + ch) = st4;
        } else {
          unsigned short* dp = vO + ((size_t)(bh8 + h) * 64 + ch) * 1024 + n;
          dp[0] = f2bf(v0); dp[1024] = f2bf(v1); dp[2048] = f2bf(v2); dp[3072] = f2bf(v3);
        }
      }
    }
  } else {
    #pragma unroll
    for (int mt = 0; mt < 4; ++mt) {
      const int m4 = m0 + wm + mt * 16 + quad * 4;
      const float b0 = bias[m4], b1 = bias[m4 + 1], b2 = bias[m4 + 2], b3 = bias[m4 + 3];
      #pragma unroll
      for (int nt = 0; nt < NFR; ++nt) {
        const int n = n0 + wn + nt * 16 + l15;
        const size_t i0 = ((size_t)b * 512 + m4) * 1024 + n;
        outf[i0]        = xres[i0]        + acc[mt][nt][0] + b0;
        outf[i0 + 1024] = xres[i0 + 1024] + acc[mt][nt][1] + b1;
        outf[i0 + 2048] = xres[i0 + 2048] + acc[mt][nt][2] + b2;
        outf[i0 + 3072] = xres[i0 + 3072] + acc[mt][nt][3] + b3;
      }
    }
  }
}

// -------- Flash attention: 8 waves/block, 256 q/block, 32 q/wave, 64-s K/V tiles -----
// qT/kT: [bh][1024][64] bf16 (q pre-scaled by 0.125*log2e); v: [bh][64][1024] bf16.
// grid (64,4): id = bh + 64*t -> XCD = bh%8 (a head's t-blocks share an XCD L2).
// THIS ROUND (T3+T4 port): 4-slot LDS ring (4 x 16KB = 64KB), prefetch depth 3,
// counted s_waitcnt vmcnt(6) -- NEVER drained to 0 in the main loop -- with raw
// s_barrier pairs per tile (barrier A: done reading t-1 before slot reuse; issue
// t+3; own-wave vmcnt; barrier B: tile t resident for all waves). Loads get ~3
// tile-windows to land instead of 1, and the m97-style vmcnt(0) barrier drain is gone.
// 8 waves share one K/V stream: staging issue cost and L2 traffic halve vs 2x4-wave.
__global__ __launch_bounds__(512) void attn_kernel(const unsigned short* __restrict__ qT,
                                                   const unsigned short* __restrict__ kT,
                                                   const unsigned short* __restrict__ vv,
                                                   unsigned short* __restrict__ aT) {
  const int bh = blockIdx.x;
  const int t0 = blockIdx.y * 256;
  const unsigned short* qb = qT + (size_t)bh * 1024 * 64;
  const unsigned short* kb = kT + (size_t)bh * 1024 * 64;
  const unsigned short* vb = vv + (size_t)bh * 64 * 1024;

  // ring[slot][0] = K tile [64s][64ch], ring[slot][1] = V tile [64c][64s]; 64KB total
  __shared__ __align__(16) unsigned short ring[4][2][64][64];

  const int tid = threadIdx.x, w = tid >> 6, lane = tid & 63;
  const int l31 = lane & 31, h = lane >> 5;
  const int srow = lane >> 3;
  const int scol = ((lane & 7) ^ srow) * 8;

  // ---- stage Q (256 rows = 32KB) through ring slots 0-1, read B-frags ----
  #pragma unroll
  for (int jj = 0; jj < 4; ++jj) {
    const int seg = w * 4 + jj;              // 32 segs of 8 rows
    GLL16(qb + (size_t)(t0 + seg * 8 + srow) * 64 + scol, &ring[0][0][0][0] + seg * 8 * 64);
  }
  __syncthreads();
  v8s qf[4];
  {
    const int row = w * 32 + l31;            // row&7 == l31&7 (swizzle-consistent)
    const unsigned short* qr = &ring[0][0][0][0] + row * 64;
    const int rx = row & 7;
    #pragma unroll
    for (int kb2 = 0; kb2 < 4; ++kb2)
      qf[kb2] = *(const v8s*)(qr + ((kb2 * 2 + h) ^ rx) * 8);
  }
  __syncthreads();   // all waves done reading Q before ring is overwritten

  // ---- prologue: issue K/V tiles 0..2 (2 GLL16 per wave per tile) ----
  #pragma unroll
  for (int tt = 0; tt < 3; ++tt) {
    const int s1 = tt * 64;
    #pragma unroll
    for (int jj = 0; jj < 2; ++jj) {
      if (w < 4) {
        const int rg = (w * 2 + jj) * 8;
        GLL16(kb + (size_t)(s1 + rg + srow) * 64 + scol, &ring[tt][0][rg][0]);
      } else {
        const int cg = ((w - 4) * 2 + jj) * 8;
        GLL16(vb + (size_t)(cg + srow) * 1024 + s1 + scol, &ring[tt][1][cg][0]);
      }
    }
  }

  f32x16 o[2];
  #pragma unroll
  for (int cb = 0; cb < 2; ++cb)
    #pragma unroll
    for (int r = 0; r < 16; ++r) o[cb][r] = 0.f;
  float lsum = 0.f;

  #pragma unroll
  for (int t = 0; t < 16; ++t) {
    // barrier A: every wave finished READING tile t-1 (its slot is about to be reused)
    asm volatile("s_barrier" ::: "memory");
    if (t + 3 < 16) {                        // issue tile t+3 into slot (t-1)&3
      const int s1 = (t + 3) * 64, sl = (t + 3) & 3;
      #pragma unroll
      for (int jj = 0; jj < 2; ++jj) {
        if (w < 4) {
          const int rg = (w * 2 + jj) * 8;
          GLL16(kb + (size_t)(s1 + rg + srow) * 64 + scol, &ring[sl][0][rg][0]);
        } else {
          const int cg = ((w - 4) * 2 + jj) * 8;
          GLL16(vb + (size_t)(cg + srow) * 1024 + s1 + scol, &ring[sl][1][cg][0]);
        }
      }
    }
    // counted wait: own tile-t loads done; t+1..t+3 (6 loads) stay in flight
    if (t < 13)       asm volatile("s_waitcnt vmcnt(6)" ::: "memory");
    else if (t == 13) asm volatile("s_waitcnt vmcnt(4)" ::: "memory");
    else if (t == 14) asm volatile("s_waitcnt vmcnt(2)" ::: "memory");
    else              asm volatile("s_waitcnt vmcnt(0)" ::: "memory");
    // barrier B: tile t resident for ALL waves
    asm volatile("s_barrier" ::: "memory");

    const int sl = t & 3;
    const unsigned short* Kb = &ring[sl][0][0][0];
    const unsigned short* Vb = &ring[sl][1][0][0];

    v8s kf[2][4], vf[2][4];
    #pragma unroll
    for (int sb = 0; sb < 2; ++sb) {
      const int row = sb * 32 + l31, rx = row & 7;
      const unsigned short* kr = Kb + row * 64;
      #pragma unroll
      for (int kb2 = 0; kb2 < 4; ++kb2)
        kf[sb][kb2] = *(const v8s*)(kr + ((kb2 * 2 + h) ^ rx) * 8);
    }
    #pragma unroll
    for (int cb = 0; cb < 2; ++cb) {
      const int row = cb * 32 + l31, rx = row & 7;
      const unsigned short* vr = Vb + row * 64;
      #pragma unroll
      for (int i = 0; i < 4; ++i)          // i = 16-wide s-block within this 64-s tile
        vf[cb][i] = *(const v8s*)(vr + ((i * 2 + h) ^ rx) * 8);
    }

    #pragma unroll
    for (int sb = 0; sb < 2; ++sb) {
      // S^T(32s x 32t) = K * Q^T over 64 ch (4 chained k-blocks)
      f32x16 sa = {0.f,0.f,0.f,0.f,0.f,0.f,0.f,0.f,0.f,0.f,0.f,0.f,0.f,0.f,0.f,0.f};
      #pragma unroll
      for (int kb2 = 0; kb2 < 4; ++kb2)
        sa = MFMA32(kf[sb][kb2], qf[kb2], sa);
      // softmax without max subtraction (q pre-scaled by log2e)
      float p[16]; float rsum = 0.f;
      #pragma unroll
      for (int r = 0; r < 16; ++r) { p[r] = exp2n(sa[r]); rsum += p[r]; }
      lsum += rsum;
      // pack P -> two 32x32x16 A-fragments (s 0..15 and 16..31)
      unsigned c0 = cvtpk(p[0], p[1]),  c1 = cvtpk(p[2], p[3]);
      unsigned c2 = cvtpk(p[4], p[5]),  c3 = cvtpk(p[6], p[7]);
      pl32swap(c0, c2); pl32swap(c1, c3);
      unsigned c4 = cvtpk(p[8], p[9]),  c5 = cvtpk(p[10], p[11]);
      unsigned c6 = cvtpk(p[12], p[13]), c7 = cvtpk(p[14], p[15]);
      pl32swap(c4, c6); pl32swap(c5, c7);
      union { v8s v; unsigned u[4]; } pa0, pa1;
      pa0.u[0] = c0; pa0.u[1] = c1; pa0.u[2] = c2; pa0.u[3] = c3;
      pa1.u[0] = c4; pa1.u[1] = c5; pa1.u[2] = c6; pa1.u[3] = c7;
      // O(32t x 64c) += P * V
      #pragma unroll
      for (int cb = 0; cb < 2; ++cb) {
        o[cb] = MFMA32(pa0.v, vf[cb][sb * 2 + 0], o[cb]);
        o[cb] = MFMA32(pa1.v, vf[cb][sb * 2 + 1], o[cb]);
      }
    }
  }

  // final l reduce across halves; write aT[b][t][hd*64+c] = O[t][c] / l(t)
  const int b = bh >> 3, hd = bh & 7;
  lsum += __shfl_xor(lsum, 32);
  #pragma unroll
  for (int r = 0; r < 16; ++r) {
    const int trow = (r & 3) + 8 * (r >> 2) + 4 * h;
    const float inv = 1.0f / __shfl(lsum, trow);
    const int t = t0 + w * 32 + trow;
    unsigned short* dst = aT + ((size_t)b * 1024 + t) * 512 + hd * 64;
    dst[l31]      = f2bf(o[0][r] * inv);
    dst[32 + l31] = f2bf(o[1][r] * inv);
  }
}

extern "C" void kernel_launch(void* const* d_in, const int* in_sizes, int n_in,
                              void* d_out, int out_size, void* d_ws, size_t ws_size,
                              hipStream_t stream) {
  const float* x    = (const float*)d_in[0];
  const float* gsc  = (const float*)d_in[1];
  const float* gbi  = (const float*)d_in[2];
  const float* qkvw = (const float*)d_in[3];
  const float* qkvb = (const float*)d_in[4];
  const float* pjw  = (const float*)d_in[5];
  const float* pjb  = (const float*)d_in[6];
  float* out = (float*)d_out;

  unsigned short* ws  = (unsigned short*)d_ws;
  unsigned short* qw  = ws;                   //  786432  qkv weights bf16
  unsigned short* pw  = qw + 786432;          //  262144  proj weights bf16
  unsigned short* xnT = pw + 262144 + 1024;   // 4194304  [b][l][c]
  unsigned short* qT  = xnT + 4194304;        // 4194304  [bh][l][64]
  unsigned short* kT  = qT + 4194304;         // 4194304  [bh][l][64]
  unsigned short* vv  = kT + 4194304;         // 4194304  [bh][64][l]
  unsigned short* aT  = vv + 4194304;         // 4194304  [b][l][c]
  // total ~44.04 MB

  cvt_gn_kernel<<<dim3(1280), dim3(256), 0, stream>>>(qkvw, qw, pjw, pw, 196608, 65536,
                                                      x, gsc, gbi, xnT);
  gemm_kernel<true, 128><<<dim3(8, 12, 8), dim3(256), 0, stream>>>(
      qw, xnT, qkvb, nullptr, nullptr, qT, kT, vv);
  attn_kernel<<<dim3(64, 4), dim3(512), 0, stream>>>(qT, kT, vv, aT);
  gemm_kernel<false, 64><<<dim3(16, 4, 8), dim3(256), 0, stream>>>(
      pw, aT, pjb, x, out, nullptr, nullptr, nullptr);
}

// Round 7
// 145.184 us; speedup vs baseline: 4.6900x; 1.6077x over previous
//
#include <hip/hip_runtime.h>
#include <hip/hip_bf16.h>

typedef __attribute__((ext_vector_type(8))) short v8s;            // 8 x bf16 (4 VGPRs) MFMA A/B
typedef __attribute__((ext_vector_type(8))) unsigned short u16x8;
typedef __attribute__((ext_vector_type(4))) float v4f;            // 16x16 MFMA C/D
typedef __attribute__((ext_vector_type(16))) float f32x16;        // 32x32 MFMA C/D

#define MFMA16(a, b, c) __builtin_amdgcn_mfma_f32_16x16x32_bf16((a), (b), (c), 0, 0, 0)
#define MFMA32(a, b, c) __builtin_amdgcn_mfma_f32_32x32x16_bf16((a), (b), (c), 0, 0, 0)

// async global->LDS, 16B per lane; LDS dest = wave-uniform base + lane*16
#define GLL16(g, l)                                                        \
  __builtin_amdgcn_global_load_lds(                                        \
      (const __attribute__((address_space(1))) unsigned int*)(g),          \
      (__attribute__((address_space(3))) unsigned int*)(l), 16, 0, 0)

#if __has_builtin(__builtin_amdgcn_exp2f)
__device__ __forceinline__ float exp2n(float x) { return __builtin_amdgcn_exp2f(x); }
#else
__device__ __forceinline__ float exp2n(float x) {
  float r; asm("v_exp_f32 %0, %1" : "=v"(r) : "v"(x)); return r;
}
#endif

__device__ __forceinline__ unsigned short f2bf(float f) {
  union { float f; unsigned u; } v; v.f = f;
  unsigned r = v.u + 0x7fffu + ((v.u >> 16) & 1u);   // RNE
  return (unsigned short)(r >> 16);
}

// RNE pack of two f32 -> bf16x2 (lo in low half) in one VOP3
__device__ __forceinline__ unsigned cvtpk(float lo, float hi) {
  unsigned r;
  asm("v_cvt_pk_bf16_f32 %0, %1, %2" : "=v"(r) : "v"(lo), "v"(hi));
  return r;
}
// gfx950: swap high 32 lanes of a with low 32 lanes of b (both modified)
__device__ __forceinline__ void pl32swap(unsigned& a, unsigned& b) {
  asm("v_permlane32_swap_b32 %0, %1" : "+v"(a), "+v"(b));
}

// ---- fused: weight fp32->bf16 convert + GroupNorm (stats+normalize+transpose) ----
__global__ __launch_bounds__(256) void cvt_gn_kernel(const float* __restrict__ in0,
                                                     unsigned short* __restrict__ out0,
                                                     const float* __restrict__ in1,
                                                     unsigned short* __restrict__ out1,
                                                     int n0, int n1,
                                                     const float* __restrict__ x,
                                                     const float* __restrict__ gsc,
                                                     const float* __restrict__ gbi,
                                                     unsigned short* __restrict__ xnT) {
  __shared__ __align__(16) float xsf[16384];   // 64KB slab, exactly at the LDS cap
  if (blockIdx.x < 1024) {
    int i = blockIdx.x * 256 + threadIdx.x;
    const float* in; unsigned short* out;
    if (i < n0) { in = in0; out = out0; }
    else        { i -= n0; if (i >= n1) return; in = in1; out = out1; }
    float4 v = ((const float4*)in)[i];
    ushort4 o;
    o.x = f2bf(v.x); o.y = f2bf(v.y); o.z = f2bf(v.z); o.w = f2bf(v.w);
    ((ushort4*)out)[i] = o;
    return;
  }
  const int bg = blockIdx.x - 1024;            // 0..255 = b*32 + g
  const int b = bg >> 5, g = bg & 31;
  const int tid = threadIdx.x;
  const float4* xp4 = (const float4*)(x + (size_t)bg * 16384);
  float4* xs4 = (float4*)xsf;
  float s = 0.f, ss = 0.f;
  #pragma unroll
  for (int k = 0; k < 16; ++k) {
    const int i = k * 256 + tid;
    float4 v = xp4[i];
    xs4[i] = v;
    s  += (v.x + v.y) + (v.z + v.w);
    ss += (v.x * v.x + v.y * v.y) + (v.z * v.z + v.w * v.w);
  }
  #pragma unroll
  for (int d = 1; d < 64; d <<= 1) { s += __shfl_xor(s, d); ss += __shfl_xor(ss, d); }
  // cross-wave reduce through slab slots 0..9 (save/clobber/restore)
  __syncthreads();
  float save = 0.f;
  if (tid < 10) save = xsf[tid];
  __syncthreads();
  if ((tid & 63) == 0) { xsf[(tid >> 6) * 2] = s; xsf[(tid >> 6) * 2 + 1] = ss; }
  __syncthreads();
  if (tid == 0) {
    const float S  = xsf[0] + xsf[2] + xsf[4] + xsf[6];
    const float SS = xsf[1] + xsf[3] + xsf[5] + xsf[7];
    const float mu  = S * (1.f / 16384.f);
    const float var = SS * (1.f / 16384.f) - mu * mu;
    xsf[8] = mu; xsf[9] = rsqrtf(var + 1e-5f);
  }
  __syncthreads();
  const float mu = xsf[8], rs = xsf[9];
  __syncthreads();
  if (tid < 10) xsf[tid] = save;
  __syncthreads();
  float scv[16], biv[16];
  #pragma unroll
  for (int j = 0; j < 16; ++j) {
    scv[j] = gsc[g * 16 + j] * rs;
    biv[j] = gbi[g * 16 + j] - mu * scv[j];
  }
  unsigned short* dp = xnT + (size_t)b * 1024 * 512 + g * 16;
  #pragma unroll
  for (int k = 0; k < 4; ++k) {
    const int l = k * 256 + tid;
    u16x8 o0, o1;
    #pragma unroll
    for (int j = 0; j < 8; ++j) o0[j] = f2bf(xsf[j * 1024 + l] * scv[j] + biv[j]);
    #pragma unroll
    for (int j = 0; j < 8; ++j) o1[j] = f2bf(xsf[(8 + j) * 1024 + l] * scv[8 + j] + biv[8 + j]);
    *(u16x8*)(dp + (size_t)l * 512)     = o0;
    *(u16x8*)(dp + (size_t)l * 512 + 8) = o1;
  }
}

// ---------------- 128xNT MFMA GEMM, BK=64, xor-swizzled 128B LDS rows ----------------
template <bool QKV, int NT>
__global__ __launch_bounds__(256) void gemm_kernel(
    const unsigned short* __restrict__ A,
    const unsigned short* __restrict__ BT,
    const float* __restrict__ bias,
    const float* __restrict__ xres,
    float* __restrict__ outf,
    unsigned short* __restrict__ qT,
    unsigned short* __restrict__ kT,
    unsigned short* __restrict__ vO) {
  constexpr int K = 512;
  constexpr int NFR = NT / 32;              // n-frags per wave
  constexpr int NJOB = 16 + NT / 8;         // staging jobs (A:16, B:NT/8)
  const int n0 = blockIdx.x * NT, m0 = blockIdx.y * 128, b = blockIdx.z;
  const unsigned short* Bp = BT + (size_t)b * 1024 * K;

  __shared__ __align__(16) unsigned short As[128][64];
  __shared__ __align__(16) unsigned short Bs[NT][64];

  const int tid = threadIdx.x, lane = tid & 63, w = tid >> 6;
  const int quad = lane >> 4, l15 = lane & 15;
  const int wm = (w >> 1) * 64, wn = (w & 1) * (NT / 2);
  const int srow = lane >> 3;
  const int scol = ((lane & 7) ^ srow) * 8;
  const int ck0 = ((quad ^ (l15 & 7)) * 8);
  const int ck1 = ck0 ^ 32;
  const unsigned short* Asf = &As[0][0];
  const unsigned short* Bsf = &Bs[0][0];

  v4f acc[4][NFR];
  #pragma unroll
  for (int i = 0; i < 4; ++i)
    #pragma unroll
    for (int j = 0; j < NFR; ++j) acc[i][j] = (v4f){0.f, 0.f, 0.f, 0.f};

  for (int kk = 0; kk < K; kk += 64) {
    __syncthreads();
    #pragma unroll
    for (int jj = 0; jj < NJOB / 4; ++jj) {
      const int job = w * (NJOB / 4) + jj;
      if (job < 16) {
        GLL16(A + (size_t)(m0 + job * 8 + srow) * K + kk + scol, &As[job * 8][0]);
      } else {
        const int j2 = job - 16;
        GLL16(Bp + (size_t)(n0 + j2 * 8 + srow) * K + kk + scol, &Bs[j2 * 8][0]);
      }
    }
    __syncthreads();
    #pragma unroll
    for (int h = 0; h < 2; ++h) {
      const int ck = h ? ck1 : ck0;
      v8s af[4], bf[NFR];
      #pragma unroll
      for (int mt = 0; mt < 4; ++mt) af[mt] = *(const v8s*)(Asf + (wm + mt * 16 + l15) * 64 + ck);
      #pragma unroll
      for (int nt = 0; nt < NFR; ++nt) bf[nt] = *(const v8s*)(Bsf + (wn + nt * 16 + l15) * 64 + ck);
      #pragma unroll
      for (int mt = 0; mt < 4; ++mt)
        #pragma unroll
        for (int nt = 0; nt < NFR; ++nt)
          acc[mt][nt] = MFMA16(af[mt], bf[nt], acc[mt][nt]);
    }
  }

  if (QKV) {
    const int bh8 = b * 8;
    const float cs = 0.18033688011112042f;   // 0.125 * log2(e), folded into q
    #pragma unroll
    for (int mt = 0; mt < 4; ++mt) {
      const int m4 = m0 + wm + mt * 16 + quad * 4;
      const int h = m4 / 192;
      const int rr = m4 - h * 192;
      const int part = rr >> 6;                          // 0=q 1=k 2=v
      const int ch = rr & 63;
      const float b0 = bias[m4], b1 = bias[m4 + 1], b2 = bias[m4 + 2], b3 = bias[m4 + 3];
      #pragma unroll
      for (int nt = 0; nt < NFR; ++nt) {
        const int n = n0 + wn + nt * 16 + l15;
        v4f a = acc[mt][nt];
        const float v0 = a[0] + b0, v1 = a[1] + b1, v2 = a[2] + b2, v3 = a[3] + b3;
        if (part == 0) {
          ushort4 st4;
          st4.x = f2bf(v0 * cs); st4.y = f2bf(v1 * cs);
          st4.z = f2bf(v2 * cs); st4.w = f2bf(v3 * cs);
          *(ushort4*)(qT + ((size_t)(bh8 + h) * 1024 + n) * 64 + ch) = st4;
        } else if (part == 1) {
          ushort4 st4;
          st4.x = f2bf(v0); st4.y = f2bf(v1); st4.z = f2bf(v2); st4.w = f2bf(v3);
          *(ushort4*)(kT + ((size_t)(bh8 + h) * 1024 + n) * 64 + ch) = st4;
        } else {
          unsigned short* dp = vO + ((size_t)(bh8 + h) * 64 + ch) * 1024 + n;
          dp[0] = f2bf(v0); dp[1024] = f2bf(v1); dp[2048] = f2bf(v2); dp[3072] = f2bf(v3);
        }
      }
    }
  } else {
    #pragma unroll
    for (int mt = 0; mt < 4; ++mt) {
      const int m4 = m0 + wm + mt * 16 + quad * 4;
      const float b0 = bias[m4], b1 = bias[m4 + 1], b2 = bias[m4 + 2], b3 = bias[m4 + 3];
      #pragma unroll
      for (int nt = 0; nt < NFR; ++nt) {
        const int n = n0 + wn + nt * 16 + l15;
        const size_t i0 = ((size_t)b * 512 + m4) * 1024 + n;
        outf[i0]        = xres[i0]        + acc[mt][nt][0] + b0;
        outf[i0 + 1024] = xres[i0 + 1024] + acc[mt][nt][1] + b1;
        outf[i0 + 2048] = xres[i0 + 2048] + acc[mt][nt][2] + b2;
        outf[i0 + 3072] = xres[i0 + 3072] + acc[mt][nt][3] + b3;
      }
    }
  }
}

// -------- Flash attention: 128q/block, 32 q/wave, 64-s K/V tiles, 32KB LDS ----------
// qT/kT: [bh][1024][64] bf16 (q pre-scaled by 0.125*log2e); v: [bh][64][1024] bf16.
// grid (64,8): id = bh + 64*t -> XCD = bh%8 (a head's t-blocks share an XCD L2).
// R4 template (compiler-managed __syncthreads double-buffer -- known race-free,
// absmax-verified) with ONE parameter change: KVBLK 128 -> 64, LDS 64KB -> 32KB.
// Occupancy: VGPR ~168 -> 12 waves/CU; LDS 32KB -> 5 blocks; binding = VGPR ->
// 3 blocks/CU (was 2), 1.5x TLP for this latency-bound kernel. Accumulation order
// unchanged (s = 0..1023 in sequence) -> result must be BIT-identical to R4
// (absmax 0.015625 is the race detector).
__global__ __launch_bounds__(256) void attn_kernel(const unsigned short* __restrict__ qT,
                                                   const unsigned short* __restrict__ kT,
                                                   const unsigned short* __restrict__ vv,
                                                   unsigned short* __restrict__ aT) {
  const int bh = blockIdx.x;
  const int t0 = blockIdx.y * 128;
  const unsigned short* qb = qT + (size_t)bh * 1024 * 64;
  const unsigned short* kb = kT + (size_t)bh * 1024 * 64;
  const unsigned short* vb = vv + (size_t)bh * 64 * 1024;

  __shared__ __align__(16) unsigned short Ks[2][64][64];   // 16KB [buf][s][ch]
  __shared__ __align__(16) unsigned short Vs[2][64][64];   // 16KB [buf][c][s64]

  const int tid = threadIdx.x, w = tid >> 6, lane = tid & 63;
  const int l31 = lane & 31, h = lane >> 5;
  const int srow = lane >> 3;
  const int scol = ((lane & 7) ^ srow) * 8;

  // ---- stage Q (128 rows = 16KB) through Ks[0..1], read B-frags ----
  #pragma unroll
  for (int jj = 0; jj < 4; ++jj) {
    const int seg = w * 4 + jj;              // 16 segs of 8 rows
    GLL16(qb + (size_t)(t0 + seg * 8 + srow) * 64 + scol, &Ks[0][0][0] + seg * 8 * 64);
  }
  __syncthreads();
  v8s qf[4];
  {
    const int row = w * 32 + l31;            // row&7 == l31&7 (swizzle-consistent)
    const unsigned short* qr = &Ks[0][0][0] + row * 64;
    const int rx = row & 7;
    #pragma unroll
    for (int kb2 = 0; kb2 < 4; ++kb2)
      qf[kb2] = *(const v8s*)(qr + ((kb2 * 2 + h) ^ rx) * 8);
  }
  __syncthreads();   // all waves done reading Q before Ks is overwritten

  // ---- stage K/V tile 0 (64 s): 16 jobs of 8 rows, 4 per wave ----
  #pragma unroll
  for (int jj = 0; jj < 4; ++jj) {
    const int j = w * 4 + jj;
    if (j < 8) {
      GLL16(kb + (size_t)(j * 8 + srow) * 64 + scol, &Ks[0][j * 8][0]);
    } else {
      const int cg = (j - 8) * 8;
      GLL16(vb + (size_t)(cg + srow) * 1024 + scol, &Vs[0][cg][0]);
    }
  }

  f32x16 o[2];
  #pragma unroll
  for (int cb = 0; cb < 2; ++cb)
    #pragma unroll
    for (int r = 0; r < 16; ++r) o[cb][r] = 0.f;
  float lsum = 0.f;

  for (int t = 0; t < 16; ++t) {
    __syncthreads();          // tile(t) resident (drains prefetch issued last iter);
                              // also: all waves done reading buf^1 before its reuse
    if (t + 1 < 16) {         // prefetch tile t+1 before compute of tile t
      const int s1 = (t + 1) * 64, bp = (t + 1) & 1;
      #pragma unroll
      for (int jj = 0; jj < 4; ++jj) {
        const int j = w * 4 + jj;
        if (j < 8) {
          GLL16(kb + (size_t)(s1 + j * 8 + srow) * 64 + scol, &Ks[bp][j * 8][0]);
        } else {
          const int cg = (j - 8) * 8;
          GLL16(vb + (size_t)(cg + srow) * 1024 + s1 + scol, &Vs[bp][cg][0]);
        }
      }
    }
    const int buf = t & 1;
    const unsigned short* Kb = &Ks[buf][0][0];
    const unsigned short* Vb = &Vs[buf][0][0];

    // hoist K (A-frag: m = s = l31 + 32*sb) and V (B-frag: n = c = l31 + 32*cb)
    v8s kf[2][4], vf[2][4];
    #pragma unroll
    for (int sb = 0; sb < 2; ++sb) {
      const int row = sb * 32 + l31, rx = row & 7;
      const unsigned short* kr = Kb + row * 64;
      #pragma unroll
      for (int kb2 = 0; kb2 < 4; ++kb2)
        kf[sb][kb2] = *(const v8s*)(kr + ((kb2 * 2 + h) ^ rx) * 8);
    }
    #pragma unroll
    for (int cb = 0; cb < 2; ++cb) {
      const int row = cb * 32 + l31, rx = row & 7;
      const unsigned short* vr = Vb + row * 64;
      #pragma unroll
      for (int i = 0; i < 4; ++i)          // i = 16-wide s-block within this 64-s tile
        vf[cb][i] = *(const v8s*)(vr + ((i * 2 + h) ^ rx) * 8);
    }

    #pragma unroll
    for (int sb = 0; sb < 2; ++sb) {
      // S^T(32s x 32t) = K * Q^T over 64 ch (4 chained k-blocks)
      f32x16 sa = {0.f,0.f,0.f,0.f,0.f,0.f,0.f,0.f,0.f,0.f,0.f,0.f,0.f,0.f,0.f,0.f};
      #pragma unroll
      for (int kb2 = 0; kb2 < 4; ++kb2)
        sa = MFMA32(kf[sb][kb2], qf[kb2], sa);
      // softmax without max subtraction (q pre-scaled by log2e)
      float p[16]; float rsum = 0.f;
      #pragma unroll
      for (int r = 0; r < 16; ++r) { p[r] = exp2n(sa[r]); rsum += p[r]; }
      lsum += rsum;
      // pack P -> two 32x32x16 A-fragments (s 0..15 and 16..31)
      unsigned c0 = cvtpk(p[0], p[1]),  c1 = cvtpk(p[2], p[3]);
      unsigned c2 = cvtpk(p[4], p[5]),  c3 = cvtpk(p[6], p[7]);
      pl32swap(c0, c2); pl32swap(c1, c3);
      unsigned c4 = cvtpk(p[8], p[9]),  c5 = cvtpk(p[10], p[11]);
      unsigned c6 = cvtpk(p[12], p[13]), c7 = cvtpk(p[14], p[15]);
      pl32swap(c4, c6); pl32swap(c5, c7);
      union { v8s v; unsigned u[4]; } pa0, pa1;
      pa0.u[0] = c0; pa0.u[1] = c1; pa0.u[2] = c2; pa0.u[3] = c3;
      pa1.u[0] = c4; pa1.u[1] = c5; pa1.u[2] = c6; pa1.u[3] = c7;
      // O(32t x 64c) += P * V
      #pragma unroll
      for (int cb = 0; cb < 2; ++cb) {
        o[cb] = MFMA32(pa0.v, vf[cb][sb * 2 + 0], o[cb]);
        o[cb] = MFMA32(pa1.v, vf[cb][sb * 2 + 1], o[cb]);
      }
    }
  }

  // final l reduce across halves; write aT[b][t][hd*64+c] = O[t][c] / l(t)
  const int b = bh >> 3, hd = bh & 7;
  lsum += __shfl_xor(lsum, 32);
  #pragma unroll
  for (int r = 0; r < 16; ++r) {
    const int trow = (r & 3) + 8 * (r >> 2) + 4 * h;
    const float inv = 1.0f / __shfl(lsum, trow);
    const int t = t0 + w * 32 + trow;
    unsigned short* dst = aT + ((size_t)b * 1024 + t) * 512 + hd * 64;
    dst[l31]      = f2bf(o[0][r] * inv);
    dst[32 + l31] = f2bf(o[1][r] * inv);
  }
}

extern "C" void kernel_launch(void* const* d_in, const int* in_sizes, int n_in,
                              void* d_out, int out_size, void* d_ws, size_t ws_size,
                              hipStream_t stream) {
  const float* x    = (const float*)d_in[0];
  const float* gsc  = (const float*)d_in[1];
  const float* gbi  = (const float*)d_in[2];
  const float* qkvw = (const float*)d_in[3];
  const float* qkvb = (const float*)d_in[4];
  const float* pjw  = (const float*)d_in[5];
  const float* pjb  = (const float*)d_in[6];
  float* out = (float*)d_out;

  unsigned short* ws  = (unsigned short*)d_ws;
  unsigned short* qw  = ws;                   //  786432  qkv weights bf16
  unsigned short* pw  = qw + 786432;          //  262144  proj weights bf16
  unsigned short* xnT = pw + 262144 + 1024;   // 4194304  [b][l][c]
  unsigned short* qT  = xnT + 4194304;        // 4194304  [bh][l][64]
  unsigned short* kT  = qT + 4194304;         // 4194304  [bh][l][64]
  unsigned short* vv  = kT + 4194304;         // 4194304  [bh][64][l]
  unsigned short* aT  = vv + 4194304;         // 4194304  [b][l][c]
  // total ~44.04 MB

  cvt_gn_kernel<<<dim3(1280), dim3(256), 0, stream>>>(qkvw, qw, pjw, pw, 196608, 65536,
                                                      x, gsc, gbi, xnT);
  gemm_kernel<true, 128><<<dim3(8, 12, 8), dim3(256), 0, stream>>>(
      qw, xnT, qkvb, nullptr, nullptr, qT, kT, vv);
  attn_kernel<<<dim3(64, 8), dim3(256), 0, stream>>>(qT, kT, vv, aT);
  gemm_kernel<false, 64><<<dim3(16, 4, 8), dim3(256), 0, stream>>>(
      pw, aT, pjb, x, out, nullptr, nullptr, nullptr);
}

// Round 8
// 141.004 us; speedup vs baseline: 4.8290x; 1.0296x over previous
//
#include <hip/hip_runtime.h>
#include <hip/hip_bf16.h>

typedef __attribute__((ext_vector_type(8))) short v8s;            // 8 x bf16 (4 VGPRs) MFMA A/B
typedef __attribute__((ext_vector_type(8))) unsigned short u16x8;
typedef __attribute__((ext_vector_type(4))) float v4f;            // 16x16 MFMA C/D
typedef __attribute__((ext_vector_type(16))) float f32x16;        // 32x32 MFMA C/D

#define MFMA16(a, b, c) __builtin_amdgcn_mfma_f32_16x16x32_bf16((a), (b), (c), 0, 0, 0)
#define MFMA32(a, b, c) __builtin_amdgcn_mfma_f32_32x32x16_bf16((a), (b), (c), 0, 0, 0)

// async global->LDS, 16B per lane; LDS dest = wave-uniform base + lane*16
#define GLL16(g, l)                                                        \
  __builtin_amdgcn_global_load_lds(                                        \
      (const __attribute__((address_space(1))) unsigned int*)(g),          \
      (__attribute__((address_space(3))) unsigned int*)(l), 16, 0, 0)

#if __has_builtin(__builtin_amdgcn_exp2f)
__device__ __forceinline__ float exp2n(float x) { return __builtin_amdgcn_exp2f(x); }
#else
__device__ __forceinline__ float exp2n(float x) {
  float r; asm("v_exp_f32 %0, %1" : "=v"(r) : "v"(x)); return r;
}
#endif

__device__ __forceinline__ unsigned short f2bf(float f) {
  union { float f; unsigned u; } v; v.f = f;
  unsigned r = v.u + 0x7fffu + ((v.u >> 16) & 1u);   // RNE
  return (unsigned short)(r >> 16);
}

// RNE pack of two f32 -> bf16x2 (lo in low half) in one VOP3
__device__ __forceinline__ unsigned cvtpk(float lo, float hi) {
  unsigned r;
  asm("v_cvt_pk_bf16_f32 %0, %1, %2" : "=v"(r) : "v"(lo), "v"(hi));
  return r;
}
// gfx950: swap high 32 lanes of a with low 32 lanes of b (both modified)
__device__ __forceinline__ void pl32swap(unsigned& a, unsigned& b) {
  asm("v_permlane32_swap_b32 %0, %1" : "+v"(a), "+v"(b));
}

// ---- fused: weight fp32->bf16 convert + GroupNorm (stats+normalize+transpose) ----
__global__ __launch_bounds__(256) void cvt_gn_kernel(const float* __restrict__ in0,
                                                     unsigned short* __restrict__ out0,
                                                     const float* __restrict__ in1,
                                                     unsigned short* __restrict__ out1,
                                                     int n0, int n1,
                                                     const float* __restrict__ x,
                                                     const float* __restrict__ gsc,
                                                     const float* __restrict__ gbi,
                                                     unsigned short* __restrict__ xnT) {
  __shared__ __align__(16) float xsf[16384];   // 64KB slab, exactly at the LDS cap
  if (blockIdx.x < 1024) {
    int i = blockIdx.x * 256 + threadIdx.x;
    const float* in; unsigned short* out;
    if (i < n0) { in = in0; out = out0; }
    else        { i -= n0; if (i >= n1) return; in = in1; out = out1; }
    float4 v = ((const float4*)in)[i];
    ushort4 o;
    o.x = f2bf(v.x); o.y = f2bf(v.y); o.z = f2bf(v.z); o.w = f2bf(v.w);
    ((ushort4*)out)[i] = o;
    return;
  }
  const int bg = blockIdx.x - 1024;            // 0..255 = b*32 + g
  const int b = bg >> 5, g = bg & 31;
  const int tid = threadIdx.x;
  const float4* xp4 = (const float4*)(x + (size_t)bg * 16384);
  float4* xs4 = (float4*)xsf;
  float s = 0.f, ss = 0.f;
  #pragma unroll
  for (int k = 0; k < 16; ++k) {
    const int i = k * 256 + tid;
    float4 v = xp4[i];
    xs4[i] = v;
    s  += (v.x + v.y) + (v.z + v.w);
    ss += (v.x * v.x + v.y * v.y) + (v.z * v.z + v.w * v.w);
  }
  #pragma unroll
  for (int d = 1; d < 64; d <<= 1) { s += __shfl_xor(s, d); ss += __shfl_xor(ss, d); }
  // cross-wave reduce through slab slots 0..9 (save/clobber/restore)
  __syncthreads();
  float save = 0.f;
  if (tid < 10) save = xsf[tid];
  __syncthreads();
  if ((tid & 63) == 0) { xsf[(tid >> 6) * 2] = s; xsf[(tid >> 6) * 2 + 1] = ss; }
  __syncthreads();
  if (tid == 0) {
    const float S  = xsf[0] + xsf[2] + xsf[4] + xsf[6];
    const float SS = xsf[1] + xsf[3] + xsf[5] + xsf[7];
    const float mu  = S * (1.f / 16384.f);
    const float var = SS * (1.f / 16384.f) - mu * mu;
    xsf[8] = mu; xsf[9] = rsqrtf(var + 1e-5f);
  }
  __syncthreads();
  const float mu = xsf[8], rs = xsf[9];
  __syncthreads();
  if (tid < 10) xsf[tid] = save;
  __syncthreads();
  float scv[16], biv[16];
  #pragma unroll
  for (int j = 0; j < 16; ++j) {
    scv[j] = gsc[g * 16 + j] * rs;
    biv[j] = gbi[g * 16 + j] - mu * scv[j];
  }
  unsigned short* dp = xnT + (size_t)b * 1024 * 512 + g * 16;
  #pragma unroll
  for (int k = 0; k < 4; ++k) {
    const int l = k * 256 + tid;
    u16x8 o0, o1;
    #pragma unroll
    for (int j = 0; j < 8; ++j) o0[j] = f2bf(xsf[j * 1024 + l] * scv[j] + biv[j]);
    #pragma unroll
    for (int j = 0; j < 8; ++j) o1[j] = f2bf(xsf[(8 + j) * 1024 + l] * scv[8 + j] + biv[8 + j]);
    *(u16x8*)(dp + (size_t)l * 512)     = o0;
    *(u16x8*)(dp + (size_t)l * 512 + 8) = o1;
  }
}

// ---------------- 128xNT MFMA GEMM, BK=64, xor-swizzled 128B LDS rows ----------------
template <bool QKV, int NT>
__global__ __launch_bounds__(256) void gemm_kernel(
    const unsigned short* __restrict__ A,
    const unsigned short* __restrict__ BT,
    const float* __restrict__ bias,
    const float* __restrict__ xres,
    float* __restrict__ outf,
    unsigned short* __restrict__ qT,
    unsigned short* __restrict__ kT,
    unsigned short* __restrict__ vO) {
  constexpr int K = 512;
  constexpr int NFR = NT / 32;              // n-frags per wave
  constexpr int NJOB = 16 + NT / 8;         // staging jobs (A:16, B:NT/8)
  const int n0 = blockIdx.x * NT, m0 = blockIdx.y * 128, b = blockIdx.z;
  const unsigned short* Bp = BT + (size_t)b * 1024 * K;

  __shared__ __align__(16) unsigned short As[128][64];
  __shared__ __align__(16) unsigned short Bs[NT][64];

  const int tid = threadIdx.x, lane = tid & 63, w = tid >> 6;
  const int quad = lane >> 4, l15 = lane & 15;
  const int wm = (w >> 1) * 64, wn = (w & 1) * (NT / 2);
  const int srow = lane >> 3;
  const int scol = ((lane & 7) ^ srow) * 8;
  const int ck0 = ((quad ^ (l15 & 7)) * 8);
  const int ck1 = ck0 ^ 32;
  const unsigned short* Asf = &As[0][0];
  const unsigned short* Bsf = &Bs[0][0];

  v4f acc[4][NFR];
  #pragma unroll
  for (int i = 0; i < 4; ++i)
    #pragma unroll
    for (int j = 0; j < NFR; ++j) acc[i][j] = (v4f){0.f, 0.f, 0.f, 0.f};

  for (int kk = 0; kk < K; kk += 64) {
    __syncthreads();
    #pragma unroll
    for (int jj = 0; jj < NJOB / 4; ++jj) {
      const int job = w * (NJOB / 4) + jj;
      if (job < 16) {
        GLL16(A + (size_t)(m0 + job * 8 + srow) * K + kk + scol, &As[job * 8][0]);
      } else {
        const int j2 = job - 16;
        GLL16(Bp + (size_t)(n0 + j2 * 8 + srow) * K + kk + scol, &Bs[j2 * 8][0]);
      }
    }
    __syncthreads();
    #pragma unroll
    for (int h = 0; h < 2; ++h) {
      const int ck = h ? ck1 : ck0;
      v8s af[4], bf[NFR];
      #pragma unroll
      for (int mt = 0; mt < 4; ++mt) af[mt] = *(const v8s*)(Asf + (wm + mt * 16 + l15) * 64 + ck);
      #pragma unroll
      for (int nt = 0; nt < NFR; ++nt) bf[nt] = *(const v8s*)(Bsf + (wn + nt * 16 + l15) * 64 + ck);
      #pragma unroll
      for (int mt = 0; mt < 4; ++mt)
        #pragma unroll
        for (int nt = 0; nt < NFR; ++nt)
          acc[mt][nt] = MFMA16(af[mt], bf[nt], acc[mt][nt]);
    }
  }

  if (QKV) {
    const int bh8 = b * 8;
    const float cs = 0.18033688011112042f;   // 0.125 * log2(e), folded into q
    #pragma unroll
    for (int mt = 0; mt < 4; ++mt) {
      const int m4 = m0 + wm + mt * 16 + quad * 4;
      const int h = m4 / 192;
      const int rr = m4 - h * 192;
      const int part = rr >> 6;                          // 0=q 1=k 2=v
      const int ch = rr & 63;
      const float b0 = bias[m4], b1 = bias[m4 + 1], b2 = bias[m4 + 2], b3 = bias[m4 + 3];
      #pragma unroll
      for (int nt = 0; nt < NFR; ++nt) {
        const int n = n0 + wn + nt * 16 + l15;
        v4f a = acc[mt][nt];
        const float v0 = a[0] + b0, v1 = a[1] + b1, v2 = a[2] + b2, v3 = a[3] + b3;
        if (part == 0) {
          ushort4 st4;
          st4.x = f2bf(v0 * cs); st4.y = f2bf(v1 * cs);
          st4.z = f2bf(v2 * cs); st4.w = f2bf(v3 * cs);
          *(ushort4*)(qT + ((size_t)(bh8 + h) * 1024 + n) * 64 + ch) = st4;
        } else if (part == 1) {
          ushort4 st4;
          st4.x = f2bf(v0); st4.y = f2bf(v1); st4.z = f2bf(v2); st4.w = f2bf(v3);
          *(ushort4*)(kT + ((size_t)(bh8 + h) * 1024 + n) * 64 + ch) = st4;
        } else {
          unsigned short* dp = vO + ((size_t)(bh8 + h) * 64 + ch) * 1024 + n;
          dp[0] = f2bf(v0); dp[1024] = f2bf(v1); dp[2048] = f2bf(v2); dp[3072] = f2bf(v3);
        }
      }
    }
  } else {
    #pragma unroll
    for (int mt = 0; mt < 4; ++mt) {
      const int m4 = m0 + wm + mt * 16 + quad * 4;
      const float b0 = bias[m4], b1 = bias[m4 + 1], b2 = bias[m4 + 2], b3 = bias[m4 + 3];
      #pragma unroll
      for (int nt = 0; nt < NFR; ++nt) {
        const int n = n0 + wn + nt * 16 + l15;
        const size_t i0 = ((size_t)b * 512 + m4) * 1024 + n;
        outf[i0]        = xres[i0]        + acc[mt][nt][0] + b0;
        outf[i0 + 1024] = xres[i0 + 1024] + acc[mt][nt][1] + b1;
        outf[i0 + 2048] = xres[i0 + 2048] + acc[mt][nt][2] + b2;
        outf[i0 + 3072] = xres[i0 + 3072] + acc[mt][nt][3] + b3;
      }
    }
  }
}

// ---------------- Flash attention: 128q/block, 32 q/wave, 128-s K/V tiles ------------
// qT/kT: [bh][1024][64] bf16 (q pre-scaled by 0.125*log2e); v: [bh][64][1024] bf16.
// grid (64,8): id = bh + 64*t -> XCD = bh%8 (a head's t-blocks share an XCD L2).
// R4 geometry (best measured: 142.5 us total), sync template UNCHANGED. Two additive
// micro-opts this round:
//  (1) prologue overlap: V-tile-0 staging (waves 2-3, Vs LDS is disjoint from the Q
//      staging area in Ks) is issued CONCURRENTLY with Q staging; only K-tile-0
//      (waves 0-1, reuses Ks[0]) waits for the Q-fragment reads. Startup critical
//      path loses one V-tile HBM latency.
//  (2) T5 s_setprio(1/0) around each hf compute cluster (m191: +4-7% attn, safe hint).
// Arithmetic order identical -> result must be BIT-identical (absmax 0.015625).
__global__ __launch_bounds__(256) void attn_kernel(const unsigned short* __restrict__ qT,
                                                   const unsigned short* __restrict__ kT,
                                                   const unsigned short* __restrict__ vv,
                                                   unsigned short* __restrict__ aT) {
  const int bh = blockIdx.x;
  const int t0 = blockIdx.y * 128;
  const unsigned short* qb = qT + (size_t)bh * 1024 * 64;
  const unsigned short* kb = kT + (size_t)bh * 1024 * 64;
  const unsigned short* vb = vv + (size_t)bh * 64 * 1024;

  __shared__ __align__(16) unsigned short Ks[2][128][64];    // 32KB [buf][s][k]
  __shared__ __align__(16) unsigned short Vs[2][2][64][64];  // 32KB [buf][s-half][c][s64]

  const int tid = threadIdx.x, w = tid >> 6, lane = tid & 63;
  const int l31 = lane & 31, h = lane >> 5;
  const int srow = lane >> 3;
  const int scol = ((lane & 7) ^ srow) * 8;

  // ---- stage Q (128 rows = 16KB) into Ks[0]; waves 2-3 issue V-tile-0 in parallel ----
  #pragma unroll
  for (int jj = 0; jj < 4; ++jj) {
    const int seg = w * 4 + jj;              // 16 segs of 8 rows
    GLL16(qb + (size_t)(t0 + seg * 8 + srow) * 64 + scol, &Ks[0][0][0] + seg * 8 * 64);
  }
  if (w >= 2) {                              // V0: Vs[0] disjoint from Q's Ks[0]
    #pragma unroll
    for (int jj = 0; jj < 8; ++jj) {
      const int j2 = (w - 2) * 8 + jj;       // 16 V jobs of 8 c-rows
      const int hf = j2 >> 3, cg = (j2 & 7) * 8;
      GLL16(vb + (size_t)(cg + srow) * 1024 + hf * 64 + scol, &Vs[0][hf][cg][0]);
    }
  }
  __syncthreads();                           // Q (and V0) resident
  v8s qf[4];
  {
    const int row = w * 32 + l31;            // row&7 == l31&7 (swizzle-consistent)
    const unsigned short* qr = &Ks[0][0][0] + row * 64;
    const int rx = row & 7;
    #pragma unroll
    for (int kb2 = 0; kb2 < 4; ++kb2)
      qf[kb2] = *(const v8s*)(qr + ((kb2 * 2 + h) ^ rx) * 8);
  }
  __syncthreads();   // all waves done reading Q before Ks is overwritten

  // ---- waves 0-1: stage K tile 0 (128 s rows) into Ks[0] ----
  if (w < 2) {
    #pragma unroll
    for (int jj = 0; jj < 8; ++jj) {
      const int j = w * 8 + jj;              // 16 K jobs of 8 rows
      GLL16(kb + (size_t)(j * 8 + srow) * 64 + scol, &Ks[0][j * 8][0]);
    }
  }

  f32x16 o[2];
  #pragma unroll
  for (int cb = 0; cb < 2; ++cb)
    #pragma unroll
    for (int r = 0; r < 16; ++r) o[cb][r] = 0.f;
  float lsum = 0.f;

  for (int it = 0; it < 8; ++it) {
    __syncthreads();          // tile(it) resident (drains prefetch issued last iter);
                              // also: all waves done reading buf^1 before its reuse
    if (it + 1 < 8) {         // prefetch tile it+1 before compute of tile it
      const int s1 = (it + 1) * 128, bp1 = (it + 1) & 1;
      #pragma unroll
      for (int jj = 0; jj < 8; ++jj) {
        const int j = w * 8 + jj;
        if (j < 16) {
          GLL16(kb + (size_t)(s1 + j * 8 + srow) * 64 + scol, &Ks[bp1][j * 8][0]);
        } else {
          const int j2 = j - 16, hf = j2 >> 3, cg = (j2 & 7) * 8;
          GLL16(vb + (size_t)(cg + srow) * 1024 + s1 + hf * 64 + scol,
                &Vs[bp1][hf][cg][0]);
        }
      }
    }
    const int buf = it & 1;

    #pragma unroll
    for (int hf = 0; hf < 2; ++hf) {
      const unsigned short* Kb = &Ks[buf][hf * 64][0];
      const unsigned short* Vb = &Vs[buf][hf][0][0];

      // hoist K (A-frag: m = s = l31 + 32*sb) and V (B-frag: n = c = l31 + 32*cb)
      v8s kf[2][4], vf[2][4];
      #pragma unroll
      for (int sb = 0; sb < 2; ++sb) {
        const int row = sb * 32 + l31, rx = row & 7;
        const unsigned short* kr = Kb + row * 64;
        #pragma unroll
        for (int kb2 = 0; kb2 < 4; ++kb2)
          kf[sb][kb2] = *(const v8s*)(kr + ((kb2 * 2 + h) ^ rx) * 8);
      }
      #pragma unroll
      for (int cb = 0; cb < 2; ++cb) {
        const int row = cb * 32 + l31, rx = row & 7;
        const unsigned short* vr = Vb + row * 64;
        #pragma unroll
        for (int i = 0; i < 4; ++i)      // i = 16-wide s-block within this 64-s half
          vf[cb][i] = *(const v8s*)(vr + ((i * 2 + h) ^ rx) * 8);
      }

      __builtin_amdgcn_s_setprio(1);     // T5: favor this wave through the MFMA cluster
      #pragma unroll
      for (int sb = 0; sb < 2; ++sb) {
        // S^T(32s x 32t) = K * Q^T over 64 ch (4 chained k-blocks)
        f32x16 sa = {0.f,0.f,0.f,0.f,0.f,0.f,0.f,0.f,0.f,0.f,0.f,0.f,0.f,0.f,0.f,0.f};
        #pragma unroll
        for (int kb2 = 0; kb2 < 4; ++kb2)
          sa = MFMA32(kf[sb][kb2], qf[kb2], sa);
        // softmax without max subtraction (q pre-scaled by log2e)
        float p[16]; float rsum = 0.f;
        #pragma unroll
        for (int r = 0; r < 16; ++r) { p[r] = exp2n(sa[r]); rsum += p[r]; }
        lsum += rsum;
        // pack P -> two 32x32x16 A-fragments (s 0..15 and 16..31)
        unsigned c0 = cvtpk(p[0], p[1]),  c1 = cvtpk(p[2], p[3]);
        unsigned c2 = cvtpk(p[4], p[5]),  c3 = cvtpk(p[6], p[7]);
        pl32swap(c0, c2); pl32swap(c1, c3);
        unsigned c4 = cvtpk(p[8], p[9]),  c5 = cvtpk(p[10], p[11]);
        unsigned c6 = cvtpk(p[12], p[13]), c7 = cvtpk(p[14], p[15]);
        pl32swap(c4, c6); pl32swap(c5, c7);
        union { v8s v; unsigned u[4]; } pa0, pa1;
        pa0.u[0] = c0; pa0.u[1] = c1; pa0.u[2] = c2; pa0.u[3] = c3;
        pa1.u[0] = c4; pa1.u[1] = c5; pa1.u[2] = c6; pa1.u[3] = c7;
        // O(32t x 64c) += P * V
        #pragma unroll
        for (int cb = 0; cb < 2; ++cb) {
          o[cb] = MFMA32(pa0.v, vf[cb][sb * 2 + 0], o[cb]);
          o[cb] = MFMA32(pa1.v, vf[cb][sb * 2 + 1], o[cb]);
        }
      }
      __builtin_amdgcn_s_setprio(0);
    }
  }

  // final l reduce across halves; write aT[b][t][hd*64+c] = O[t][c] / l(t)
  const int b = bh >> 3, hd = bh & 7;
  lsum += __shfl_xor(lsum, 32);
  #pragma unroll
  for (int r = 0; r < 16; ++r) {
    const int trow = (r & 3) + 8 * (r >> 2) + 4 * h;
    const float inv = 1.0f / __shfl(lsum, trow);
    const int t = t0 + w * 32 + trow;
    unsigned short* dst = aT + ((size_t)b * 1024 + t) * 512 + hd * 64;
    dst[l31]      = f2bf(o[0][r] * inv);
    dst[32 + l31] = f2bf(o[1][r] * inv);
  }
}

extern "C" void kernel_launch(void* const* d_in, const int* in_sizes, int n_in,
                              void* d_out, int out_size, void* d_ws, size_t ws_size,
                              hipStream_t stream) {
  const float* x    = (const float*)d_in[0];
  const float* gsc  = (const float*)d_in[1];
  const float* gbi  = (const float*)d_in[2];
  const float* qkvw = (const float*)d_in[3];
  const float* qkvb = (const float*)d_in[4];
  const float* pjw  = (const float*)d_in[5];
  const float* pjb  = (const float*)d_in[6];
  float* out = (float*)d_out;

  unsigned short* ws  = (unsigned short*)d_ws;
  unsigned short* qw  = ws;                   //  786432  qkv weights bf16
  unsigned short* pw  = qw + 786432;          //  262144  proj weights bf16
  unsigned short* xnT = pw + 262144 + 1024;   // 4194304  [b][l][c]
  unsigned short* qT  = xnT + 4194304;        // 4194304  [bh][l][64]
  unsigned short* kT  = qT + 4194304;         // 4194304  [bh][l][64]
  unsigned short* vv  = kT + 4194304;         // 4194304  [bh][64][l]
  unsigned short* aT  = vv + 4194304;         // 4194304  [b][l][c]
  // total ~44.04 MB

  cvt_gn_kernel<<<dim3(1280), dim3(256), 0, stream>>>(qkvw, qw, pjw, pw, 196608, 65536,
                                                      x, gsc, gbi, xnT);
  gemm_kernel<true, 128><<<dim3(8, 12, 8), dim3(256), 0, stream>>>(
      qw, xnT, qkvb, nullptr, nullptr, qT, kT, vv);
  attn_kernel<<<dim3(64, 8), dim3(256), 0, stream>>>(qT, kT, vv, aT);
  gemm_kernel<false, 64><<<dim3(16, 4, 8), dim3(256), 0, stream>>>(
      pw, aT, pjb, x, out, nullptr, nullptr, nullptr);
}